// Round 13
// baseline (921.910 us; speedup 1.0000x reference)
//
#include <hip/hip_runtime.h>
#include <hip/hip_bf16.h>

// NEmbNet R13: FUSED L2+L3 kernel. h1 never hits global: per-wave 32x128 LDS
// tile (XOR-swizzled), X accumulates in registers across 8 W1 n-tiles, softmax
// +scatter in-kernel (R10's proven 128-row path). No h1 buffer -> MC=4096 is
// L3-safe (live 162MB < 256MB), 6 launches total. L1 = frozen R6 gemm97 core.

typedef short v8s __attribute__((ext_vector_type(8)));
typedef float v4f __attribute__((ext_vector_type(4)));
using bf16 = __hip_bfloat16;

#define AS_GLOBAL __attribute__((address_space(1)))
#define AS_LDS    __attribute__((address_space(3)))

static constexpr int Mtot = 8192;
static constexpr int Fdim = 512;
static constexpr int Hdim = 1024;
static constexpr int Pdim = 64;
static constexpr int Aexp = 16;

__device__ __forceinline__ void gload_lds16(const void* g, void* l) {
  __builtin_amdgcn_global_load_lds((const AS_GLOBAL void*)g, (AS_LDS void*)l, 16, 0, 0);
}
__device__ __forceinline__ unsigned short bfu(float x) {
  bf16 h = __float2bfloat16(x);
  return *(unsigned short*)&h;
}
#define MFMA16(d, a, b) d = __builtin_amdgcn_mfma_f32_16x16x32_bf16(a, b, d, 0, 0, 0)
#define BAR() __builtin_amdgcn_s_barrier()

__device__ __forceinline__ void cvt_span(const float* __restrict__ src,
                                         unsigned short* __restrict__ dst, int n4,
                                         int gid, int nthr) {
  for (int i = gid; i < n4; i += nthr) {
    float4 v = ((const float4*)src)[i];
    ushort4 u;
    u.x = bfu(v.x); u.y = bfu(v.y); u.z = bfu(v.z); u.w = bfu(v.w);
    ((ushort4*)dst)[i] = u;
  }
}

// ---------------------------------------------------------------- cvt all inputs
__global__ void cvt_all_kernel(const float* __restrict__ s0, unsigned short* __restrict__ d0, int n0,
                               const float* __restrict__ s1, unsigned short* __restrict__ d1, int n1,
                               const float* __restrict__ s2, unsigned short* __restrict__ d2, int n2,
                               const float* __restrict__ s3, unsigned short* __restrict__ d3, int n3) {
  int gid = blockIdx.x * blockDim.x + threadIdx.x;
  int nthr = gridDim.x * blockDim.x;
  cvt_span(s0, d0, n0, gid, nthr);
  cvt_span(s1, d1, n1, gid, nthr);
  cvt_span(s2, d2, n2, gid, nthr);
  cvt_span(s3, d3, n3, gid, nthr);
}

// ---------------------------------------------------------------- partial identity fill
__global__ void ident_kernel(float* __restrict__ outp, const int* __restrict__ aidx) {
  unsigned long long act = 0;
#pragma unroll
  for (int i = 0; i < Aexp; ++i) act |= 1ull << (aidx[i] & 63);
  const long total4 = (long)Mtot * Pdim * Pdim / 4;
  long i = blockIdx.x * 256 + threadIdx.x;
  const long stride = (long)gridDim.x * 256;
  for (; i < total4; i += stride) {
    long e = i * 4;
    int q = (int)(e & 63);
    int p = (int)((e >> 6) & 63);
    if ((act >> p) & 1) continue;
    v4f v;
    v[0] = (p == q) ? 1.f : 0.f;
    v[1] = (p == q + 1) ? 1.f : 0.f;
    v[2] = (p == q + 2) ? 1.f : 0.f;
    v[3] = (p == q + 3) ? 1.f : 0.f;
    __builtin_nontemporal_store(v, (v4f*)&outp[e]);
  }
}

// ---------------------------------------------------------------- L1 GEMM (R6 core, frozen)
template <int NT>  // K = NT*64 == A row stride
__global__ __launch_bounds__(256) void gemm97_kernel(
    const bf16* __restrict__ Ain, long aAmul,
    const bf16* __restrict__ Bw,
    const float* __restrict__ bias,
    bf16* __restrict__ Cout, long aCmul, int nbm) {
  constexpr int K = NT * 64;
  __shared__ short lsA[128 * 64];
  __shared__ short lsB[128 * 64];
  const int t = threadIdx.x;
  const int nwg = nbm * 128;

  const int flat = blockIdx.x;
  const int perx = nwg >> 3;
  const int swz = (flat & 7) * perx + (flat >> 3);
  const int perg = nbm * 8;
  const int g = swz / perg;
  const int e = swz % perg;
  const int msup = e >> 5;
  const int ny = (e >> 2) & 7;
  const int mloc = e & 3;
  const int mBase = (msup * 4 + mloc) * 128;
  const int nBase = ny * 128;

  const bf16* A0 = Ain + (size_t)g * aAmul;
  const bf16* B0 = Bw + (size_t)g * (1024 * K);
  const float* biasE = bias + g * 1024 + nBase;
  bf16* C0 = Cout + (size_t)g * aCmul + nBase;

  const int w = t >> 6, lane = t & 63;
  const int wm = w >> 1, wn = w & 1;
  const int lr = lane & 15, lk = lane >> 4;

  v4f acc[4][4];
#pragma unroll
  for (int m = 0; m < 4; ++m)
#pragma unroll
    for (int n = 0; n < 4; ++n) acc[m][n] = (v4f)(0.f);

  const int rowA = t >> 3;
  const int sg = (t & 7) ^ (rowA & 7);
  const bf16* gA = A0 + (size_t)(mBase + rowA) * K + sg * 8;
  const bf16* gB = B0 + (size_t)(nBase + rowA) * K + sg * 8;

  for (int k0 = 0; k0 < K; k0 += 64) {
#pragma unroll
    for (int i = 0; i < 4; ++i) {
      gload_lds16(gA + (size_t)(i * 32) * K + k0, &lsA[i * 2048 + t * 8]);
      gload_lds16(gB + (size_t)(i * 32) * K + k0, &lsB[i * 2048 + t * 8]);
    }
    __syncthreads();
#pragma unroll
    for (int kk = 0; kk < 2; ++kk) {
      v8s af[4], bfr[4];
#pragma unroll
      for (int m = 0; m < 4; ++m) {
        const int row = wm * 64 + m * 16 + lr;
        af[m] = *(const v8s*)&lsA[row * 64 + ((((kk << 2) + lk) ^ (row & 7)) << 3)];
      }
#pragma unroll
      for (int n = 0; n < 4; ++n) {
        const int row = wn * 64 + n * 16 + lr;
        bfr[n] = *(const v8s*)&lsB[row * 64 + ((((kk << 2) + lk) ^ (row & 7)) << 3)];
      }
#pragma unroll
      for (int m = 0; m < 4; ++m)
#pragma unroll
        for (int n = 0; n < 4; ++n)
          MFMA16(acc[m][n], af[m], bfr[n]);
    }
    __syncthreads();
  }

#pragma unroll
  for (int n = 0; n < 4; ++n) {
    const int colIn = wn * 64 + n * 16 + lr;
    const float bv = biasE[colIn];
#pragma unroll
    for (int m = 0; m < 4; ++m) {
      const int row0 = mBase + wm * 64 + m * 16 + lk * 4;
#pragma unroll
      for (int j = 0; j < 4; ++j) {
        float v = acc[m][n][j] + bv;
        v = v > 0.f ? v : 0.f;
        C0[(size_t)(row0 + j) * 1024 + colIn] = __float2bfloat16(v);
      }
    }
  }
}

// ---------------------------------------------------------------- FUSED L2 + L3 + softmax + scatter
// Block: 128 h0-rows x 1 expert, 4 waves (wave w owns rows w*32..+31).
// For ntile 0..7: K=1024 GEMM into acc2 (32x128/wave) -> relu+bf16 -> wave-
// private LDS h1 tile -> X (32x64/wave, registers) += h1t @ W2[:,slice]^T.
// Then softmax over learned cols + scatter (R10-proven path). h1 never global.
__global__ __launch_bounds__(256) void fused23_kernel(
    const bf16* __restrict__ h0, long aAmul,
    const bf16* __restrict__ W1b, const float* __restrict__ b1,
    const bf16* __restrict__ W2b, const float* __restrict__ ltl,
    const int* __restrict__ lidx, const int* __restrict__ aidx,
    float* __restrict__ outp, int mGlobBase, int nbm) {
  __shared__ short lsA[128 * 64];
  __shared__ short lsB[128 * 64];
  __shared__ char uni[128 * 68 * 4];  // h1t (4 waves x 8KB) ; X[128][68] overlays
  __shared__ int s_lidx[32];
  __shared__ int s_inv[64];
  __shared__ int s_arow;

  const int t = threadIdx.x;
  const int nwg = nbm * Aexp;
  const int flat = blockIdx.x;
  const int perx = nwg >> 3;
  const int swz = (flat & 7) * perx + (flat >> 3);
  const int g = swz / nbm;
  const int mBase = (swz % nbm) * 128;

  if (t < 64) s_inv[t] = -1;
  __syncthreads();
  if (t < 32) {
    int q = lidx[t];
    s_lidx[t] = q;
    s_inv[q] = t;
  }
  if (t == 0) s_arow = aidx[g];

  const int w = t >> 6, lane = t & 63;
  const int wm = w;
  const int lr = lane & 15, lk = lane >> 4;

  const bf16* A0 = h0 + (size_t)g * aAmul;
  const bf16* W1g = W1b + (size_t)g * (Hdim * Hdim);
  const bf16* W2g = W2b + (size_t)g * (Pdim * Hdim);
  const float* b1g = b1 + g * Hdim;
  const float* ltlE = ltl + g * Pdim;

  const int srow = t >> 3;
  const int sg = (t & 7) ^ (srow & 7);
  const bf16* gA = A0 + (size_t)(mBase + srow) * Hdim + sg * 8;
  const bf16* gBW = W1g + (size_t)srow * Hdim + sg * 8;

  auto stage = [&](int ntile, int kt) {
#pragma unroll
    for (int i = 0; i < 4; ++i) {
      gload_lds16(gA + (size_t)(i * 32) * Hdim + kt * 64, &lsA[i * 2048 + t * 8]);
      gload_lds16(gBW + (size_t)(ntile * 128 + i * 32) * Hdim + kt * 64,
                  &lsB[i * 2048 + t * 8]);
    }
  };

  unsigned short* h1t = (unsigned short*)uni + w * 4096;  // [32][128] u16, XOR-swz
  float(*X)[68] = (float(*)[68])uni;

  v4f xac[2][4];
#pragma unroll
  for (int m = 0; m < 2; ++m)
#pragma unroll
    for (int n = 0; n < 4; ++n) xac[m][n] = (v4f)(0.f);

  stage(0, 0);

  for (int ntile = 0; ntile < 8; ++ntile) {
    v4f acc2[2][8];
#pragma unroll
    for (int m = 0; m < 2; ++m)
#pragma unroll
      for (int n = 0; n < 8; ++n) acc2[m][n] = (v4f)(0.f);

    for (int kt = 0; kt < 16; ++kt) {
      __syncthreads();
#pragma unroll
      for (int ks = 0; ks < 2; ++ks) {
        v8s af[2], bfr[8];
#pragma unroll
        for (int m = 0; m < 2; ++m) {
          const int row = wm * 32 + m * 16 + lr;
          af[m] = *(const v8s*)&lsA[row * 64 + ((((ks << 2) + lk) ^ (row & 7)) << 3)];
        }
#pragma unroll
        for (int n = 0; n < 8; ++n) {
          const int row = n * 16 + lr;
          bfr[n] = *(const v8s*)&lsB[row * 64 + ((((ks << 2) + lk) ^ (row & 7)) << 3)];
        }
#pragma unroll
        for (int m = 0; m < 2; ++m)
#pragma unroll
          for (int n = 0; n < 8; ++n)
            MFMA16(acc2[m][n], af[m], bfr[n]);
      }
      __syncthreads();
      if (kt < 15) stage(ntile, kt + 1);
      else if (ntile < 7) stage(ntile + 1, 0);
    }

    // h1 tile -> wave-private LDS (bias+relu+bf16), XOR-swizzled
#pragma unroll
    for (int n = 0; n < 8; ++n) {
      const int col = n * 16 + lr;
      const float bv = b1g[ntile * 128 + col];
#pragma unroll
      for (int m = 0; m < 2; ++m) {
#pragma unroll
        for (int j = 0; j < 4; ++j) {
          const int row = m * 16 + lk * 4 + j;
          float v = acc2[m][n][j] + bv;
          v = v > 0.f ? v : 0.f;
          h1t[row * 128 + ((((col >> 3) ^ (row & 7)) << 3) | (col & 7))] = bfu(v);
        }
      }
    }
    asm volatile("s_waitcnt lgkmcnt(0)" ::: "memory");
    __builtin_amdgcn_sched_barrier(0);

    // L3: X += h1t @ W2[:, ntile-slice]^T  (A from wave-private LDS, B from global)
#pragma unroll
    for (int ks = 0; ks < 4; ++ks) {
      v8s a3[2], b3[4];
#pragma unroll
      for (int m = 0; m < 2; ++m) {
        const int row = m * 16 + lr;
        a3[m] = *(const v8s*)&h1t[row * 128 + ((((ks << 2) + lk) ^ (row & 7)) << 3)];
      }
#pragma unroll
      for (int n = 0; n < 4; ++n)
        b3[n] = *(const v8s*)&W2g[(size_t)(n * 16 + lr) * Hdim + ntile * 128 +
                                  ks * 32 + lk * 8];
#pragma unroll
      for (int m = 0; m < 2; ++m)
#pragma unroll
        for (int n = 0; n < 4; ++n)
          MFMA16(xac[m][n], a3[m], b3[n]);
    }
  }

  // X overlay + softmax + scatter (R10-proven 128-row path)
  __syncthreads();
#pragma unroll
  for (int n = 0; n < 4; ++n) {
    const int col = n * 16 + lr;
    const float lc = ltlE[col];
#pragma unroll
    for (int m = 0; m < 2; ++m)
#pragma unroll
      for (int j = 0; j < 4; ++j)
        X[wm * 32 + m * 16 + lk * 4 + j][col] = xac[m][n][j] + lc;
  }
  __syncthreads();

  if (t < 128) {
    const int r = t;
    float mx = -1e30f;
#pragma unroll
    for (int l = 0; l < 32; ++l) mx = fmaxf(mx, X[r][s_lidx[l]]);
    float s = 0.f;
#pragma unroll
    for (int l = 0; l < 32; ++l) s += __expf(X[r][s_lidx[l]] - mx);
    const float rs = 1.f / s;
    const size_t obase = ((size_t)(mGlobBase + mBase + r) * 64 + s_arow) * 64;
#pragma unroll
    for (int q0 = 0; q0 < 64; q0 += 4) {
      v4f v;
      v[0] = (s_inv[q0 + 0] >= 0) ? __expf(X[r][q0 + 0] - mx) * rs : 0.f;
      v[1] = (s_inv[q0 + 1] >= 0) ? __expf(X[r][q0 + 1] - mx) * rs : 0.f;
      v[2] = (s_inv[q0 + 2] >= 0) ? __expf(X[r][q0 + 2] - mx) * rs : 0.f;
      v[3] = (s_inv[q0 + 3] >= 0) ? __expf(X[r][q0 + 3] - mx) * rs : 0.f;
      __builtin_nontemporal_store(v, (v4f*)&outp[obase + q0]);
    }
  }
}

// ---------------------------------------------------------------- launch
extern "C" void kernel_launch(void* const* d_in, const int* in_sizes, int n_in,
                              void* d_out, int out_size, void* d_ws, size_t ws_size,
                              hipStream_t stream) {
  const float* state = (const float*)d_in[0];
  const float* W0 = (const float*)d_in[1];
  const float* b0 = (const float*)d_in[2];
  const float* W1 = (const float*)d_in[3];
  const float* b1 = (const float*)d_in[4];
  const float* W2 = (const float*)d_in[5];
  const float* ltl = (const float*)d_in[6];
  const int* lidx = (const int*)d_in[7];
  const int* aidx = (const int*)d_in[8];
  float* outp = (float*)d_out;

  // ws: stateb 8MiB | W0b 16 | W1b 32 | W2b 2 | h0 (Aexp*MC*2KiB)
  char* ws = (char*)d_ws;
  bf16* stateb = (bf16*)ws;
  bf16* W0b = stateb + (size_t)Mtot * Fdim;
  bf16* W1b = W0b + (size_t)Aexp * Hdim * Fdim;
  bf16* W2b = W1b + (size_t)Aexp * Hdim * Hdim;
  bf16* h0 = W2b + (size_t)Aexp * Pdim * Hdim;
  const size_t fixedB = (size_t)(Mtot * Fdim + Aexp * Hdim * Fdim +
                                 Aexp * Hdim * Hdim + Aexp * Pdim * Hdim) * 2;
  int MC = 4096;  // no h1 buffer: live set ~162MB < L3; 512-block fused grid
  while (MC > 512 && fixedB + (size_t)Aexp * MC * Hdim * 2 + 4096 > ws_size) MC >>= 1;

  ident_kernel<<<dim3(4096), dim3(256), 0, stream>>>(outp, aidx);
  cvt_all_kernel<<<dim3(2048), dim3(256), 0, stream>>>(
      state, (unsigned short*)stateb, Mtot * Fdim / 4,
      W0, (unsigned short*)W0b, Aexp * Hdim * Fdim / 4,
      W1, (unsigned short*)W1b, Aexp * Hdim * Hdim / 4,
      W2, (unsigned short*)W2b, Aexp * Pdim * Hdim / 4);

  const int nbm = MC / 128;
  for (int mOff = 0; mOff < Mtot; mOff += MC) {
    // L1: h0[g][MC][1024] = relu(state[MC,512] @ W0[g]^T + b0[g])
    gemm97_kernel<Fdim / 64><<<dim3(nbm * 128), dim3(256), 0, stream>>>(
        stateb + (size_t)mOff * Fdim, 0L,
        W0b, b0, h0, (long)MC * Hdim, nbm);
    // fused L2+L3+softmax+scatter
    fused23_kernel<<<dim3(nbm * Aexp), dim3(256), 0, stream>>>(
        h0, (long)MC * Hdim, W1b, b1, W2b, ltl, lidx, aidx, outp, mOff, nbm);
  }
}

// Round 14
// 655.933 us; speedup vs baseline: 1.4055x; 1.4055x over previous
//
#include <hip/hip_runtime.h>
#include <hip/hip_bf16.h>

// NEmbNet R14: champion consolidation = R6 (622us, best of 13 rounds) exactly,
// plus the two proven traffic-reducing deltas: partial ident (skip active rows,
// R10/R12-verified) and nontemporal out stores (R11/R12-verified).
// R6's GEMM/gemm2 cores and MC=2048 launch structure are byte-identical.
// Escape attempts that FAILED (do not retry): 8-phase 256^2 (R7 null at K<=1024),
// G=8 full-M (R9, >L3 live set), LDS-bounce epilogue (R10), full-M L1 (R11),
// MC=1024 (R12), fused L2+L3 (R13, A-restage thrash).

typedef short v8s __attribute__((ext_vector_type(8)));
typedef float v4f __attribute__((ext_vector_type(4)));
using bf16 = __hip_bfloat16;

#define AS_GLOBAL __attribute__((address_space(1)))
#define AS_LDS    __attribute__((address_space(3)))

static constexpr int Mtot = 8192;
static constexpr int Fdim = 512;
static constexpr int Hdim = 1024;
static constexpr int Pdim = 64;
static constexpr int Aexp = 16;

__device__ __forceinline__ void gload_lds16(const void* g, void* l) {
  __builtin_amdgcn_global_load_lds((const AS_GLOBAL void*)g, (AS_LDS void*)l, 16, 0, 0);
}
__device__ __forceinline__ unsigned short bfu(float x) {
  bf16 h = __float2bfloat16(x);
  return *(unsigned short*)&h;
}
#define MFMA16(d, a, b) d = __builtin_amdgcn_mfma_f32_16x16x32_bf16(a, b, d, 0, 0, 0)
#define WAIT_VM3 asm volatile("s_waitcnt vmcnt(3)" ::: "memory")
#define WAIT_VM0 asm volatile("s_waitcnt vmcnt(0)" ::: "memory")
#define BAR() __builtin_amdgcn_s_barrier()

__device__ __forceinline__ void cvt_span(const float* __restrict__ src,
                                         unsigned short* __restrict__ dst, int n4,
                                         int gid, int nthr) {
  for (int i = gid; i < n4; i += nthr) {
    float4 v = ((const float4*)src)[i];
    ushort4 u;
    u.x = bfu(v.x); u.y = bfu(v.y); u.z = bfu(v.z); u.w = bfu(v.w);
    ((ushort4*)dst)[i] = u;
  }
}

// ---------------------------------------------------------------- cvt all inputs
__global__ void cvt_all_kernel(const float* __restrict__ s0, unsigned short* __restrict__ d0, int n0,
                               const float* __restrict__ s1, unsigned short* __restrict__ d1, int n1,
                               const float* __restrict__ s2, unsigned short* __restrict__ d2, int n2,
                               const float* __restrict__ s3, unsigned short* __restrict__ d3, int n3) {
  int gid = blockIdx.x * blockDim.x + threadIdx.x;
  int nthr = gridDim.x * blockDim.x;
  cvt_span(s0, d0, n0, gid, nthr);
  cvt_span(s1, d1, n1, gid, nthr);
  cvt_span(s2, d2, n2, gid, nthr);
  cvt_span(s3, d3, n3, gid, nthr);
}

// ---------------------------------------------------------------- partial identity fill
// Identity for NON-active rows only (gemm2 rewrites active rows every call).
__global__ void ident_kernel(float* __restrict__ outp, const int* __restrict__ aidx) {
  unsigned long long act = 0;
#pragma unroll
  for (int i = 0; i < Aexp; ++i) act |= 1ull << (aidx[i] & 63);
  const long total4 = (long)Mtot * Pdim * Pdim / 4;
  long i = blockIdx.x * 256 + threadIdx.x;
  const long stride = (long)gridDim.x * 256;
  for (; i < total4; i += stride) {
    long e = i * 4;
    int q = (int)(e & 63);
    int p = (int)((e >> 6) & 63);
    if ((act >> p) & 1) continue;
    v4f v;
    v[0] = (p == q) ? 1.f : 0.f;
    v[1] = (p == q + 1) ? 1.f : 0.f;
    v[2] = (p == q + 2) ? 1.f : 0.f;
    v[3] = (p == q + 3) ? 1.f : 0.f;
    __builtin_nontemporal_store(v, (v4f*)&outp[e]);
  }
}

// ---------------------------------------------------------------- m97-style batched GEMM (R6 core, frozen)
// C[g-slice] = relu(A @ B^T + bias). 128x128, BK=64, 4 waves, T2 both-sides swizzle.
// XCD-chunk swizzle -> g -> msup -> ny(8) -> mloc(4).
template <int NT>  // K = NT*64 == A row stride
__global__ __launch_bounds__(256) void gemm97_kernel(
    const bf16* __restrict__ Ain, long aAmul,
    const bf16* __restrict__ Bw,
    const float* __restrict__ bias,
    bf16* __restrict__ Cout, long aCmul, int nbm) {
  constexpr int K = NT * 64;
  __shared__ short lsA[128 * 64];
  __shared__ short lsB[128 * 64];
  const int t = threadIdx.x;
  const int nwg = nbm * 128;

  const int flat = blockIdx.x;
  const int perx = nwg >> 3;
  const int swz = (flat & 7) * perx + (flat >> 3);
  const int perg = nbm * 8;
  const int g = swz / perg;
  const int e = swz % perg;
  const int msup = e >> 5;
  const int ny = (e >> 2) & 7;
  const int mloc = e & 3;
  const int mBase = (msup * 4 + mloc) * 128;
  const int nBase = ny * 128;

  const bf16* A0 = Ain + (size_t)g * aAmul;
  const bf16* B0 = Bw + (size_t)g * (1024 * K);
  const float* biasE = bias + g * 1024 + nBase;
  bf16* C0 = Cout + (size_t)g * aCmul + nBase;

  const int w = t >> 6, lane = t & 63;
  const int wm = w >> 1, wn = w & 1;
  const int lr = lane & 15, lk = lane >> 4;

  v4f acc[4][4];
#pragma unroll
  for (int m = 0; m < 4; ++m)
#pragma unroll
    for (int n = 0; n < 4; ++n) acc[m][n] = (v4f)(0.f);

  const int rowA = t >> 3;
  const int sg = (t & 7) ^ (rowA & 7);   // T2 pre-swizzled source granule
  const bf16* gA = A0 + (size_t)(mBase + rowA) * K + sg * 8;
  const bf16* gB = B0 + (size_t)(nBase + rowA) * K + sg * 8;

  for (int k0 = 0; k0 < K; k0 += 64) {
#pragma unroll
    for (int i = 0; i < 4; ++i) {
      gload_lds16(gA + (size_t)(i * 32) * K + k0, &lsA[i * 2048 + t * 8]);
      gload_lds16(gB + (size_t)(i * 32) * K + k0, &lsB[i * 2048 + t * 8]);
    }
    __syncthreads();
#pragma unroll
    for (int kk = 0; kk < 2; ++kk) {
      v8s af[4], bfr[4];
#pragma unroll
      for (int m = 0; m < 4; ++m) {
        const int row = wm * 64 + m * 16 + lr;
        af[m] = *(const v8s*)&lsA[row * 64 + ((((kk << 2) + lk) ^ (row & 7)) << 3)];
      }
#pragma unroll
      for (int n = 0; n < 4; ++n) {
        const int row = wn * 64 + n * 16 + lr;
        bfr[n] = *(const v8s*)&lsB[row * 64 + ((((kk << 2) + lk) ^ (row & 7)) << 3)];
      }
#pragma unroll
      for (int m = 0; m < 4; ++m)
#pragma unroll
        for (int n = 0; n < 4; ++n)
          MFMA16(acc[m][n], af[m], bfr[n]);
    }
    __syncthreads();
  }

#pragma unroll
  for (int n = 0; n < 4; ++n) {
    const int colIn = wn * 64 + n * 16 + lr;
    const float bv = biasE[colIn];
#pragma unroll
    for (int m = 0; m < 4; ++m) {
      const int row0 = mBase + wm * 64 + m * 16 + lk * 4;
#pragma unroll
      for (int j = 0; j < 4; ++j) {
        float v = acc[m][n][j] + bv;
        v = v > 0.f ? v : 0.f;
        C0[(size_t)(row0 + j) * 1024 + colIn] = __float2bfloat16(v);
      }
    }
  }
}

// ---------------------------------------------------------------- L3 + softmax + scatter (R6 core + NT out)
// grid (MC/32, 16): blockIdx.y = expert. h1 per-expert contiguous [A][MC][1024].
__global__ __launch_bounds__(256) void gemm2_softmax_kernel(
    const bf16* __restrict__ h1, const bf16* __restrict__ W2b,
    const float* __restrict__ ltl, const int* __restrict__ lidx,
    const int* __restrict__ aidx, float* __restrict__ outp, int mGlobBase, int MC) {
  __shared__ short lsA[2][32 * 64];
  __shared__ short lsB[2][64 * 64];
  __shared__ float X[32][68];
  __shared__ int s_lidx[32];
  __shared__ int s_inv[64];
  __shared__ int s_arow;
  const int a = blockIdx.y;
  const bf16* Ain = h1 + (size_t)a * MC * Hdim;
  const bf16* Bw = W2b + (size_t)a * Pdim * Hdim;
  const float* ltlE = ltl + (size_t)a * Pdim;

  const int t = threadIdx.x;
  const int mBase = blockIdx.x * 32;
  const int w = t >> 6, lane = t & 63;
  const int lr = lane & 15, lk = lane >> 4;
  const int wr = w & 1, wq = w >> 1;

  if (t < 64) s_inv[t] = -1;
  __syncthreads();
  if (t < 32) {
    int q = lidx[t];
    s_lidx[t] = q;
    s_inv[q] = t;
  }
  if (t == 0) s_arow = aidx[a];
  __syncthreads();

  const int srow = t >> 3;
  const int sg = (t & 7) ^ ((t >> 3) & 7);
  const bf16* gA = Ain + (size_t)(mBase + srow) * Hdim + sg * 8;
  const bf16* gB = Bw + (size_t)srow * Hdim + sg * 8;

  auto stage = [&](int buf, int kt) {
    gload_lds16(gA + kt * 64, &lsA[buf][t * 8]);
    gload_lds16(gB + kt * 64, &lsB[buf][t * 8]);
    gload_lds16(gB + (size_t)32 * Hdim + kt * 64, &lsB[buf][2048 + t * 8]);
  };

  v4f acc[2];
  acc[0] = (v4f)(0.f); acc[1] = (v4f)(0.f);

  stage(0, 0);
  for (int kt = 0; kt < 16; ++kt) {
    const int buf = kt & 1;
    if (kt + 1 < 16) { stage(buf ^ 1, kt + 1); WAIT_VM3; } else { WAIT_VM0; }
    BAR();
#pragma unroll
    for (int s = 0; s < 2; ++s) {
      int rowA = wr * 16 + lr;
      v8s af = *(const v8s*)&lsA[buf][rowA * 64 + ((((s << 2) + lk) ^ (rowA & 7)) << 3)];
#pragma unroll
      for (int n = 0; n < 2; ++n) {
        int rowB = wq * 32 + n * 16 + lr;
        v8s bf = *(const v8s*)&lsB[buf][rowB * 64 + ((((s << 2) + lk) ^ (rowB & 7)) << 3)];
        MFMA16(acc[n], af, bf);
      }
    }
    BAR();
  }

#pragma unroll
  for (int n = 0; n < 2; ++n) {
    const int col = wq * 32 + n * 16 + lr;
    const float lc = ltlE[col];
#pragma unroll
    for (int j = 0; j < 4; ++j) {
      X[wr * 16 + lk * 4 + j][col] = acc[n][j] + lc;
    }
  }
  __syncthreads();

  if (t < 32) {
    const int r = t;
    float mx = -1e30f;
#pragma unroll
    for (int l = 0; l < 32; ++l) mx = fmaxf(mx, X[r][s_lidx[l]]);
    float s = 0.f;
#pragma unroll
    for (int l = 0; l < 32; ++l) s += __expf(X[r][s_lidx[l]] - mx);
    const float rs = 1.f / s;
    const size_t obase = ((size_t)(mGlobBase + mBase + r) * 64 + s_arow) * 64;
#pragma unroll
    for (int q0 = 0; q0 < 64; q0 += 4) {
      v4f v;
      v[0] = (s_inv[q0 + 0] >= 0) ? __expf(X[r][q0 + 0] - mx) * rs : 0.f;
      v[1] = (s_inv[q0 + 1] >= 0) ? __expf(X[r][q0 + 1] - mx) * rs : 0.f;
      v[2] = (s_inv[q0 + 2] >= 0) ? __expf(X[r][q0 + 2] - mx) * rs : 0.f;
      v[3] = (s_inv[q0 + 3] >= 0) ? __expf(X[r][q0 + 3] - mx) * rs : 0.f;
      __builtin_nontemporal_store(v, (v4f*)&outp[obase + q0]);
    }
  }
}

// ---------------------------------------------------------------- launch
extern "C" void kernel_launch(void* const* d_in, const int* in_sizes, int n_in,
                              void* d_out, int out_size, void* d_ws, size_t ws_size,
                              hipStream_t stream) {
  const float* state = (const float*)d_in[0];
  const float* W0 = (const float*)d_in[1];
  const float* b0 = (const float*)d_in[2];
  const float* W1 = (const float*)d_in[3];
  const float* b1 = (const float*)d_in[4];
  const float* W2 = (const float*)d_in[5];
  const float* ltl = (const float*)d_in[6];
  const int* lidx = (const int*)d_in[7];
  const int* aidx = (const int*)d_in[8];
  float* outp = (float*)d_out;

  char* ws = (char*)d_ws;
  bf16* stateb = (bf16*)ws;
  bf16* W0b = stateb + (size_t)Mtot * Fdim;
  bf16* W1b = W0b + (size_t)Aexp * Hdim * Fdim;
  bf16* W2b = W1b + (size_t)Aexp * Hdim * Hdim;
  bf16* h0 = W2b + (size_t)Aexp * Pdim * Hdim;
  const size_t fixedB = (size_t)(Mtot * Fdim + Aexp * Hdim * Fdim +
                                 Aexp * Hdim * Hdim + Aexp * Pdim * Hdim) * 2;
  int MC = 2048;  // proven optimum (1024: -11%, 4096: -25%+)
  while (MC > 512 && fixedB + (size_t)2 * Aexp * MC * Hdim * 2 + 4096 > ws_size) MC >>= 1;
  bf16* h1 = h0 + (size_t)Aexp * MC * Hdim;

  ident_kernel<<<dim3(4096), dim3(256), 0, stream>>>(outp, aidx);
  cvt_all_kernel<<<dim3(2048), dim3(256), 0, stream>>>(
      state, (unsigned short*)stateb, Mtot * Fdim / 4,
      W0, (unsigned short*)W0b, Aexp * Hdim * Fdim / 4,
      W1, (unsigned short*)W1b, Aexp * Hdim * Hdim / 4,
      W2, (unsigned short*)W2b, Aexp * Pdim * Hdim / 4);

  const int nbm = MC / 128;
  for (int mOff = 0; mOff < Mtot; mOff += MC) {
    gemm97_kernel<Fdim / 64><<<dim3(nbm * 128), dim3(256), 0, stream>>>(
        stateb + (size_t)mOff * Fdim, 0L,
        W0b, b0, h0, (long)MC * Hdim, nbm);
    gemm97_kernel<Hdim / 64><<<dim3(nbm * 128), dim3(256), 0, stream>>>(
        h0, (long)MC * Hdim,
        W1b, b1, h1, (long)MC * Hdim, nbm);
    gemm2_softmax_kernel<<<dim3(MC / 32, Aexp), dim3(256), 0, stream>>>(
        h1, W2b, ltl, lidx, aidx, outp, mOff, MC);
  }
}